// Round 18
// baseline (2180.161 us; speedup 1.0000x reference)
//
#include <hip/hip_runtime.h>
#include <math.h>

#define TC 128
#define NC 4
#define BATCH 512
#define T_TOTAL 512
#define D_IN 300
#define KP1 320
#define H1 128
#define G1 512
#define H2 32
#define NCLS 14

typedef unsigned short u16;
typedef __attribute__((ext_vector_type(8))) _Float16 f16x8;
typedef __attribute__((ext_vector_type(4))) float f32x4;

__device__ __forceinline__ float fexp2(float x) { return __builtin_amdgcn_exp2f(x); }
__device__ __forceinline__ float frcp(float x)  { return __builtin_amdgcn_rcpf(x); }
__device__ __forceinline__ float sig_f(float x) { return frcp(1.0f + fexp2(-1.44269504f * x)); }
__device__ __forceinline__ float th_f(float x)  { return 1.0f - 2.0f * frcp(1.0f + fexp2(2.88539008f * x)); }

// LDS-only barrier: no vmcnt(0) drain (global loads/stores stay in flight)
__device__ __forceinline__ void lds_barrier() {
    asm volatile("s_waitcnt lgkmcnt(0)" ::: "memory");
    __builtin_amdgcn_s_barrier();
}

// ---------------------------------------------------------------------------
// Prep: permuted-column f16 planes.
// ---------------------------------------------------------------------------
__global__ void prep_weights(const float* __restrict__ U1, _Float16* __restrict__ U1p,
                             const float* __restrict__ U2, _Float16* __restrict__ U2p,
                             const float* __restrict__ W1, _Float16* __restrict__ W1T,
                             const float* __restrict__ W2, _Float16* __restrict__ W2T,
                             const float* __restrict__ b1, float* __restrict__ b1p,
                             const float* __restrict__ b2, float* __restrict__ b2p)
{
    int idx = blockIdx.x * 256 + threadIdx.x;
    if (idx < 512 * 128) {
        int p = idx >> 7, k = idx & 127;
        int orig = ((p >> 4) & 3) * 128 + ((p >> 6) << 4) + (p & 15);
        U1p[p * 128 + k] = (_Float16)U1[k * 512 + orig];
    }
    if (idx < 512 * 320) {
        int p = idx / 320, k = idx % 320;
        int orig = ((p >> 4) & 3) * 128 + ((p >> 6) << 4) + (p & 15);
        W1T[p * 320 + k] = (_Float16)((k < D_IN) ? W1[k * 512 + orig] : 0.f);
    }
    if (idx < 128 * 128) {
        int p = idx >> 7, k = idx & 127;
        int orig = ((p >> 4) & 3) * 32 + ((p >> 6) << 4) + (p & 15);
        W2T[p * 128 + k] = (_Float16)W2[k * 128 + orig];
    }
    if (idx < 128 * 32) {
        int p = idx >> 5, k = idx & 31;
        int orig = ((p >> 4) & 3) * 32 + ((p >> 6) << 4) + (p & 15);
        U2p[p * 32 + k] = (_Float16)U2[k * 128 + orig];
    }
    if (idx < 512) {
        int orig = ((idx >> 4) & 3) * 128 + ((idx >> 6) << 4) + (idx & 15);
        b1p[idx] = b1[orig];
    }
    if (idx < 128) {
        int orig = ((idx >> 4) & 3) * 32 + ((idx >> 6) << 4) + (idx & 15);
        b2p[idx] = b2[orig];
    }
}

// ---------------------------------------------------------------------------
// xsplit: x chunk -> f16 plane
// ---------------------------------------------------------------------------
__device__ __forceinline__ void xsplit_item(const float* __restrict__ x,
                                            _Float16* __restrict__ xh,
                                            int chunk, long i)
{
    int rr = (int)(i / 40), s = (int)(i % 40);
    int b = rr >> 7, tt = rr & 127;
    long m = (long)b * T_TOTAL + (long)chunk * TC + tt;
    int k0 = s * 8;
    const float* xr = x + m * D_IN + k0;
    float4 v0 = {0.f, 0.f, 0.f, 0.f}, v1 = {0.f, 0.f, 0.f, 0.f};
    if (s < 37) {
        v0 = *(const float4*)(xr);
        v1 = *(const float4*)(xr + 4);
    } else if (s == 37) {
        v0 = *(const float4*)(xr);
    }
    f16x8 o;
    o[0] = (_Float16)v0.x; o[1] = (_Float16)v0.y;
    o[2] = (_Float16)v0.z; o[3] = (_Float16)v0.w;
    o[4] = (_Float16)v1.x; o[5] = (_Float16)v1.y;
    o[6] = (_Float16)v1.z; o[7] = (_Float16)v1.w;
    *(f16x8*)(xh + m * KP1 + k0) = o;
}

__global__ void xsplit_chunk(const float* __restrict__ x, _Float16* __restrict__ xh, int chunk)
{
    long gid = (long)blockIdx.x * 256 + threadIdx.x;
    if (gid >= 65536L * 40) return;
    xsplit_item(x, xh, chunk, gid);
}

__device__ __forceinline__ void xsplit_role(const float* __restrict__ x,
                                            _Float16* __restrict__ xh,
                                            int chunk, int cwid, int ncw)
{
    const int tid = threadIdx.x;
    for (long i = (long)cwid * 512 + tid; i < 65536L * 40; i += (long)ncw * 512)
        xsplit_item(x, xh, chunk, i);
}

// ---------------------------------------------------------------------------
// GEMM m-block: WG computes C[128 rows][ALL N = NT*128 cols], row-major C.
// ---------------------------------------------------------------------------
template<int NK, int NT, bool XMAP>
__device__ __forceinline__ void gemm_mblock(
    const _Float16* __restrict__ A, const _Float16* __restrict__ B,
    const float* __restrict__ bias, float* __restrict__ C,
    int m0, int chunk)
{
    const int Nc = NT * 128;
    const int tid = threadIdx.x;
    const int l = tid & 63, w = tid >> 6;
    const int wm = w >> 2, wn = w & 3;
    const int lr = l & 15, q = l >> 4;
    const int koff = q * 8;
    const int LDA = NK * 32;

    const _Float16* ap[4];
#pragma unroll
    for (int fi = 0; fi < 4; fi++) {
        int m = m0 + wm * 64 + fi * 16 + lr;
        long row = XMAP ? ((long)(m >> 7) * T_TOTAL + (long)chunk * TC + (m & (TC - 1)))
                        : (long)m;
        ap[fi] = A + row * LDA + koff;
    }
    const _Float16* bp[NT * 2];
    float bv[NT * 2];
#pragma unroll
    for (int fj = 0; fj < NT * 2; fj++) {
        int col = (fj >> 1) * 128 + wn * 32 + (fj & 1) * 16 + lr;
        bp[fj] = B + (long)col * LDA + koff;
        bv[fj] = bias[col];
    }

    f32x4 acc[4][NT * 2];
#pragma unroll
    for (int fi = 0; fi < 4; fi++)
#pragma unroll
        for (int fj = 0; fj < NT * 2; fj++)
            acc[fi][fj] = (f32x4){bv[fj], bv[fj], bv[fj], bv[fj]};

    f16x8 acur[4], anxt[4];
#pragma unroll
    for (int fi = 0; fi < 4; fi++)
        acur[fi] = *(const f16x8*)(ap[fi]);

#pragma unroll
    for (int ks = 0; ks < NK; ks++) {
        f16x8 bb[NT * 2];
#pragma unroll
        for (int fj = 0; fj < NT * 2; fj++)
            bb[fj] = *(const f16x8*)(bp[fj] + ks * 32);
        if (ks + 1 < NK) {
#pragma unroll
            for (int fi = 0; fi < 4; fi++)
                anxt[fi] = *(const f16x8*)(ap[fi] + (ks + 1) * 32);
        }
#pragma unroll
        for (int fi = 0; fi < 4; fi++)
#pragma unroll
            for (int fj = 0; fj < NT * 2; fj++)
                acc[fi][fj] = __builtin_amdgcn_mfma_f32_16x16x32_f16(acur[fi], bb[fj], acc[fi][fj], 0, 0, 0);
#pragma unroll
        for (int fi = 0; fi < 4; fi++)
            acur[fi] = anxt[fi];
    }

#pragma unroll
    for (int fi = 0; fi < 4; fi++) {
        int mrow = m0 + wm * 64 + fi * 16 + q * 4;
#pragma unroll
        for (int fj = 0; fj < NT * 2; fj++) {
            int col = (fj >> 1) * 128 + wn * 32 + (fj & 1) * 16 + lr;
#pragma unroll
            for (int rr = 0; rr < 4; rr++)
                C[(long)(mrow + rr) * Nc + col] = acc[fi][fj][rr];
        }
    }
}

// ---------------------------------------------------------------------------
// Role A: lstm1 scan, 4 ROWS/WG over 128 WGs (paired 2/CU via bid,bid+256
// round-robin dispatch -> cross-barrier TLP). Batch row r (0..3) at A/D-tile
// position 4r = reg 0 of quarter r: each lane activates exactly 1 row from
// its own acc regs. 10 trans/lane/step, 4 xz loads, 1 c-update.
// ---------------------------------------------------------------------------
#define L1_DECL(P) float P##0, P##1, P##2, P##3;

#define L1_LOAD(P, T)                                                             \
    P##0 = xz[xr + (long)(T) * 512 +  0];                                         \
    P##1 = xz[xr + (long)(T) * 512 + 16];                                         \
    P##2 = xz[xr + (long)(T) * 512 + 32];                                         \
    P##3 = xz[xr + (long)(T) * 512 + 48];

#define L1_STEP(T, PB, XC, XN)                                                    \
{                                                                                 \
    f16x8 ah0 = *(const f16x8*)&Ah[(PB) * 2048 + lr * 128 + (((q     ) ^ lr) << 3)]; \
    f16x8 ah1 = *(const f16x8*)&Ah[(PB) * 2048 + lr * 128 + (((q +  4) ^ lr) << 3)]; \
    f16x8 ah2 = *(const f16x8*)&Ah[(PB) * 2048 + lr * 128 + (((q +  8) ^ lr) << 3)]; \
    f16x8 ah3 = *(const f16x8*)&Ah[(PB) * 2048 + lr * 128 + (((q + 12) ^ lr) << 3)]; \
    if ((T) + 1 < TC) { L1_LOAD(XN, (T) + 1) }                                    \
    f32x4 a0 = (f32x4){XC##0, 0.f, 0.f, 0.f};                                     \
    f32x4 a1 = (f32x4){XC##1, 0.f, 0.f, 0.f};                                     \
    f32x4 a2 = (f32x4){XC##2, 0.f, 0.f, 0.f};                                     \
    f32x4 a3 = (f32x4){XC##3, 0.f, 0.f, 0.f};                                     \
    a0 = __builtin_amdgcn_mfma_f32_16x16x32_f16(ah0, uh00, a0, 0, 0, 0);          \
    a1 = __builtin_amdgcn_mfma_f32_16x16x32_f16(ah0, uh10, a1, 0, 0, 0);          \
    a2 = __builtin_amdgcn_mfma_f32_16x16x32_f16(ah0, uh20, a2, 0, 0, 0);          \
    a3 = __builtin_amdgcn_mfma_f32_16x16x32_f16(ah0, uh30, a3, 0, 0, 0);          \
    a0 = __builtin_amdgcn_mfma_f32_16x16x32_f16(ah1, uh01, a0, 0, 0, 0);          \
    a1 = __builtin_amdgcn_mfma_f32_16x16x32_f16(ah1, uh11, a1, 0, 0, 0);          \
    a2 = __builtin_amdgcn_mfma_f32_16x16x32_f16(ah1, uh21, a2, 0, 0, 0);          \
    a3 = __builtin_amdgcn_mfma_f32_16x16x32_f16(ah1, uh31, a3, 0, 0, 0);          \
    a0 = __builtin_amdgcn_mfma_f32_16x16x32_f16(ah2, uh02, a0, 0, 0, 0);          \
    a1 = __builtin_amdgcn_mfma_f32_16x16x32_f16(ah2, uh12, a1, 0, 0, 0);          \
    a2 = __builtin_amdgcn_mfma_f32_16x16x32_f16(ah2, uh22, a2, 0, 0, 0);          \
    a3 = __builtin_amdgcn_mfma_f32_16x16x32_f16(ah2, uh32, a3, 0, 0, 0);          \
    a0 = __builtin_amdgcn_mfma_f32_16x16x32_f16(ah3, uh03, a0, 0, 0, 0);          \
    a1 = __builtin_amdgcn_mfma_f32_16x16x32_f16(ah3, uh13, a1, 0, 0, 0);          \
    a2 = __builtin_amdgcn_mfma_f32_16x16x32_f16(ah3, uh23, a2, 0, 0, 0);          \
    a3 = __builtin_amdgcn_mfma_f32_16x16x32_f16(ah3, uh33, a3, 0, 0, 0);          \
    {                                                                             \
        float iv = sig_f(a0[0]), fv = sig_f(a1[0]), gv = th_f(a2[0]), ov = sig_f(a3[0]); \
        cst = fv * cst + iv * gv;                                                 \
        float hv = ov * th_f(cst);                                                \
        _Float16 hh = (_Float16)hv;                                               \
        Ah[((PB) ^ 1) * 2048 + pq * 128 + idxq] = hh;                             \
        h1f[((long)(b0 + q) * TC + (T)) * 128 + cn] = hh;                         \
        if ((T) == TC - 1) {                                                      \
            s1h[(long)(b0 + q) * 128 + cn] = hv;                                  \
            s1c[(long)(b0 + q) * 128 + cn] = cst;                                 \
        }                                                                         \
    }                                                                             \
    lds_barrier();                                                                \
}

static __device__ __forceinline__ void lstm1_role(
    const float* __restrict__ xz, const _Float16* __restrict__ U1p,
    _Float16* __restrict__ h1f, float* __restrict__ s1h, float* __restrict__ s1c,
    int first, char* smc, int g)
{
    const int tid = threadIdx.x;
    const int l = tid & 63, w = tid >> 6;
    const int lr = l & 15, q = l >> 4;
    const int koff = q * 8;
    const int cn = w * 16 + lr;
    const int b0 = g * 4;                        // 4 rows per WG, 128 WGs
    const int p0 = w * 64 + lr;
    const int pq = 4 * q;                        // tile row of this lane's batch row
    const int idxq = (((cn >> 3) ^ pq) << 3) + (cn & 7);

    _Float16* Ah = (_Float16*)smc;   // [2][16][128] f16

    const long xr = ((long)(b0 + q) * TC) * 512 + p0;

    const _Float16* ub = U1p + (long)(w * 64 + lr) * 128 + koff;
    f16x8 uh00 = *(const f16x8*)(ub +    0 * 128 +  0);
    f16x8 uh01 = *(const f16x8*)(ub +    0 * 128 + 32);
    f16x8 uh02 = *(const f16x8*)(ub +    0 * 128 + 64);
    f16x8 uh03 = *(const f16x8*)(ub +    0 * 128 + 96);
    f16x8 uh10 = *(const f16x8*)(ub +   16 * 128 +  0);
    f16x8 uh11 = *(const f16x8*)(ub +   16 * 128 + 32);
    f16x8 uh12 = *(const f16x8*)(ub +   16 * 128 + 64);
    f16x8 uh13 = *(const f16x8*)(ub +   16 * 128 + 96);
    f16x8 uh20 = *(const f16x8*)(ub +   32 * 128 +  0);
    f16x8 uh21 = *(const f16x8*)(ub +   32 * 128 + 32);
    f16x8 uh22 = *(const f16x8*)(ub +   32 * 128 + 64);
    f16x8 uh23 = *(const f16x8*)(ub +   32 * 128 + 96);
    f16x8 uh30 = *(const f16x8*)(ub +   48 * 128 +  0);
    f16x8 uh31 = *(const f16x8*)(ub +   48 * 128 + 32);
    f16x8 uh32 = *(const f16x8*)(ub +   48 * 128 + 64);
    f16x8 uh33 = *(const f16x8*)(ub +   48 * 128 + 96);

    // init: tile row 4q from state; rows 4q+1..4q+3 zeroed in BOTH buffers
    float h = 0.f, cst = 0.f;
    if (!first) {
        h = s1h[(long)(b0 + q) * 128 + cn];
        cst = s1c[(long)(b0 + q) * 128 + cn];
    }
    Ah[pq * 128 + idxq] = (_Float16)h;
#pragma unroll
    for (int j = 1; j < 4; j++) {
        int p = 4 * q + j;
        int idx = (((cn >> 3) ^ p) << 3) + (cn & 7);
        Ah[p * 128 + idx] = (_Float16)0.f;
        Ah[2048 + p * 128 + idx] = (_Float16)0.f;
    }
    lds_barrier();

    L1_DECL(xa) L1_DECL(xb)
    L1_LOAD(xa, 0)

    for (int t = 0; t < TC; t += 2) {
        L1_STEP(t,     0, xa, xb)
        L1_STEP(t + 1, 1, xb, xa)
    }
}

// ---------------------------------------------------------------------------
// Role B: lstm2 scan, 16 rows/WG, WGs [64,96), waves 0-1 active.
// ---------------------------------------------------------------------------
#define L2_DECL(P) float P##00, P##01, P##02, P##03, P##10, P##11, P##12, P##13, \
                         P##20, P##21, P##22, P##23, P##30, P##31, P##32, P##33;

#define L2_LOAD(P, T)                                                             \
    P##00 = xz2[yr0 + (long)(T) * 128 +  0]; P##01 = xz2[yr1 + (long)(T) * 128 +  0]; \
    P##02 = xz2[yr2 + (long)(T) * 128 +  0]; P##03 = xz2[yr3 + (long)(T) * 128 +  0]; \
    P##10 = xz2[yr0 + (long)(T) * 128 + 16]; P##11 = xz2[yr1 + (long)(T) * 128 + 16]; \
    P##12 = xz2[yr2 + (long)(T) * 128 + 16]; P##13 = xz2[yr3 + (long)(T) * 128 + 16]; \
    P##20 = xz2[yr0 + (long)(T) * 128 + 32]; P##21 = xz2[yr1 + (long)(T) * 128 + 32]; \
    P##22 = xz2[yr2 + (long)(T) * 128 + 32]; P##23 = xz2[yr3 + (long)(T) * 128 + 32]; \
    P##30 = xz2[yr0 + (long)(T) * 128 + 48]; P##31 = xz2[yr1 + (long)(T) * 128 + 48]; \
    P##32 = xz2[yr2 + (long)(T) * 128 + 48]; P##33 = xz2[yr3 + (long)(T) * 128 + 48];

#define L2_STEP(T, PB, XC, XN)                                                    \
{                                                                                 \
    if (act) {                                                                    \
        f16x8 ah = *(const f16x8*)&Ah[(PB) * 640 + lr * 40 + koff];               \
        if ((T) + 1 < TC) { L2_LOAD(XN, (T) + 1) }                                \
        f32x4 a0 = (f32x4){XC##00, XC##01, XC##02, XC##03};                       \
        f32x4 a1 = (f32x4){XC##10, XC##11, XC##12, XC##13};                       \
        f32x4 a2 = (f32x4){XC##20, XC##21, XC##22, XC##23};                       \
        f32x4 a3 = (f32x4){XC##30, XC##31, XC##32, XC##33};                       \
        a0 = __builtin_amdgcn_mfma_f32_16x16x32_f16(ah, uh0, a0, 0, 0, 0);        \
        a1 = __builtin_amdgcn_mfma_f32_16x16x32_f16(ah, uh1, a1, 0, 0, 0);        \
        a2 = __builtin_amdgcn_mfma_f32_16x16x32_f16(ah, uh2, a2, 0, 0, 0);        \
        a3 = __builtin_amdgcn_mfma_f32_16x16x32_f16(ah, uh3, a3, 0, 0, 0);        \
        _Pragma("unroll")                                                         \
        for (int r = 0; r < 4; r++) {                                             \
            float iv = sig_f(a0[r]);                                              \
            float fv = sig_f(a1[r]);                                              \
            float gv = th_f(a2[r]);                                               \
            float ov = sig_f(a3[r]);                                              \
            float cc = (r == 0) ? cst0 : (r == 1) ? cst1 : (r == 2) ? cst2 : cst3;\
            cc = fv * cc + iv * gv;                                               \
            float hv = ov * th_f(cc);                                             \
            if (r == 0) cst0 = cc; else if (r == 1) cst1 = cc;                    \
            else if (r == 2) cst2 = cc; else cst3 = cc;                           \
            int rw = (q << 2) + r;                                                \
            Ah[((PB) ^ 1) * 640 + rw * 40 + cn] = (_Float16)hv;                   \
            if ((T) == TC - 1) {                                                  \
                s2h[(long)(b0 + rw) * 32 + cn] = hv;                              \
                s2c[(long)(b0 + rw) * 32 + cn] = cc;                              \
            }                                                                     \
        }                                                                         \
    }                                                                             \
    lds_barrier();                                                                \
}

static __device__ __forceinline__ void lstm2_role(
    const float* __restrict__ xz2, const _Float16* __restrict__ U2p,
    float* __restrict__ s2h, float* __restrict__ s2c, int first, char* smc)
{
    const int tid = threadIdx.x;
    const int b0 = (blockIdx.x - 64) * 16;
    const bool act = tid < 128;
    const int l = tid & 63, w = (tid >> 6) & 1;
    const int lr = l & 15, q = l >> 4;
    const int koff = q * 8;
    const int cn = w * 16 + lr;
    const int p0 = w * 64 + lr;
    const int bq = b0 + q * 4;

    const long yr0 = ((long)(bq + 0) * TC) * 128 + p0;
    const long yr1 = ((long)(bq + 1) * TC) * 128 + p0;
    const long yr2 = ((long)(bq + 2) * TC) * 128 + p0;
    const long yr3 = ((long)(bq + 3) * TC) * 128 + p0;

    _Float16* Ah = (_Float16*)smc;   // [2][16][40]

    f16x8 uh0 = {}, uh1 = {}, uh2 = {}, uh3 = {};
    float cst0 = 0.f, cst1 = 0.f, cst2 = 0.f, cst3 = 0.f;
    L2_DECL(xa) L2_DECL(xb)

    if (act) {
        const _Float16* ub = U2p + (long)(w * 64 + lr) * 32 + koff;
        uh0 = *(const f16x8*)(ub +  0 * 32);
        uh1 = *(const f16x8*)(ub + 16 * 32);
        uh2 = *(const f16x8*)(ub + 32 * 32);
        uh3 = *(const f16x8*)(ub + 48 * 32);
#pragma unroll
        for (int r = 0; r < 4; r++) {
            int rw = q * 4 + r;
            float h = 0.f, c = 0.f;
            if (!first) {
                h = s2h[(long)(b0 + rw) * 32 + cn];
                c = s2c[(long)(b0 + rw) * 32 + cn];
            }
            if (r == 0) cst0 = c; else if (r == 1) cst1 = c;
            else if (r == 2) cst2 = c; else cst3 = c;
            Ah[rw * 40 + cn] = (_Float16)h;
        }
        L2_LOAD(xa, 0)
    }
    lds_barrier();

    for (int t = 0; t < TC; t += 2) {
        L2_STEP(t,     0, xa, xb)
        L2_STEP(t + 1, 1, xb, xa)
    }
}

// ---------------------------------------------------------------------------
// Fused mega kernel, 512-WG grid.
// A = lstm1(cA): bids [0,64) U [256,320)  -> pairs (b, b+256) co-resident/CU.
// B = lstm2(cB): bids [64,96).
// C = xsplit(xs) + gemm1(g1) + gemm2(g2): remaining bids.
// waves_per_eu(4,4): VGPR <= 128 -> two 8-wave WGs per CU (16 waves) fit.
// ---------------------------------------------------------------------------
__global__ void
__attribute__((amdgpu_flat_work_group_size(512, 512)))
__attribute__((amdgpu_waves_per_eu(4, 4)))
mega(
    const float* __restrict__ x, _Float16* __restrict__ xh,
    const _Float16* __restrict__ W1T, const float* __restrict__ b1p,
    const _Float16* __restrict__ W2T, const float* __restrict__ b2p,
    const _Float16* __restrict__ U1p, const _Float16* __restrict__ U2p,
    float* xz1_0, float* xz1_1, float* xz2_0, float* xz2_1,
    _Float16* h1f_0, _Float16* h1f_1,
    float* s1h, float* s1c, float* s2h, float* s2c,
    int cA, int cB, int g1, int g2, int xs)
{
    __shared__ __align__(16) char sm[8192];
    int bid = blockIdx.x;

    if (cA >= 0 && (bid < 64 || (bid >= 256 && bid < 320))) {
        int g = (bid < 256) ? bid : (bid - 192);   // 0..127
        const float* xz = (cA & 1) ? xz1_1 : xz1_0;
        _Float16* hf = (cA & 1) ? h1f_1 : h1f_0;
        lstm1_role(xz, U1p, hf, s1h, s1c, cA == 0, sm, g);
        return;
    }
    if (cB >= 0 && bid >= 64 && bid < 96) {
        const float* xz2 = (cB & 1) ? xz2_1 : xz2_0;
        lstm2_role(xz2, U2p, s2h, s2c, cB == 0, sm);
        return;
    }
    // gemm worker index among non-role bids
    int rb = 0;
    if (cA >= 0) {
        rb += (bid < 64) ? bid : 64;
        int t = bid - 256; rb += (t < 0) ? 0 : ((t > 64) ? 64 : t);
    }
    if (cB >= 0) {
        int t = bid - 64; rb += (t < 0) ? 0 : ((t > 32) ? 32 : t);
    }
    int cwid = bid - rb;
    int ncw = 512 - ((cA >= 0) ? 128 : 0) - ((cB >= 0) ? 32 : 0);

    if (xs >= 0) xsplit_role(x, xh, xs, cwid, ncw);
    int ng1 = (g1 >= 0) ? (BATCH * TC / 128) : 0;   // 512 m-blocks
    int ng2 = (g2 >= 0) ? (BATCH * TC / 128) : 0;   // 512 m-blocks
    float* xz1o = (g1 >= 0 && (g1 & 1)) ? xz1_1 : xz1_0;
    float* xz2o = (g2 >= 0 && (g2 & 1)) ? xz2_1 : xz2_0;
    const _Float16* hf = (g2 >= 0 && (g2 & 1)) ? h1f_1 : h1f_0;
    for (int it = cwid; it < ng1 + ng2; it += ncw) {
        if (it < ng1)
            gemm_mblock<10, 4, true>(xh, W1T, b1p, xz1o, it * 128, g1);
        else
            gemm_mblock<4, 1, false>(hf, W2T, b2p, xz2o, (it - ng1) * 128, 0);
    }
}

// ---------------------------------------------------------------------------
// Head: out = softmax(h2_last @ Wd + bd)   [512,32]@[32,14]
// ---------------------------------------------------------------------------
__global__ __launch_bounds__(256)
void head_kernel(const float* __restrict__ h2, const float* __restrict__ Wd,
                 const float* __restrict__ bd, float* __restrict__ out)
{
    int b = blockIdx.x * 256 + threadIdx.x;
    float h[H2];
#pragma unroll
    for (int k = 0; k < H2; k += 4)
        *(float4*)&h[k] = *(const float4*)&h2[b * H2 + k];

    float lg[NCLS];
#pragma unroll
    for (int c = 0; c < NCLS; c++) lg[c] = bd[c];
#pragma unroll
    for (int k = 0; k < H2; k++) {
        float hv = h[k];
#pragma unroll
        for (int c = 0; c < NCLS; c++)
            lg[c] += hv * Wd[k * NCLS + c];
    }
    float m = lg[0];
#pragma unroll
    for (int c = 1; c < NCLS; c++) m = fmaxf(m, lg[c]);
    float s = 0.f;
#pragma unroll
    for (int c = 0; c < NCLS; c++) { lg[c] = __expf(lg[c] - m); s += lg[c]; }
    float inv = __fdividef(1.0f, s);
#pragma unroll
    for (int c = 0; c < NCLS; c++) out[b * NCLS + c] = lg[c] * inv;
}

// ---------------------------------------------------------------------------
extern "C" void kernel_launch(void* const* d_in, const int* in_sizes, int n_in,
                              void* d_out, int out_size, void* d_ws, size_t ws_size,
                              hipStream_t stream)
{
    const float* x  = (const float*)d_in[0];
    const float* W1 = (const float*)d_in[1];
    const float* U1 = (const float*)d_in[2];
    const float* b1 = (const float*)d_in[3];
    const float* W2 = (const float*)d_in[4];
    const float* U2 = (const float*)d_in[5];
    const float* b2 = (const float*)d_in[6];
    const float* Wd = (const float*)d_in[7];
    const float* bd = (const float*)d_in[8];
    float* out = (float*)d_out;

    char* ws = (char*)d_ws;
    float* xz1[2]    = {(float*)(ws + 0L),         (float*)(ws + 134217728L)};
    _Float16* xh     = (_Float16*)(ws + 268435456L);               // 167772160
    _Float16* h1f[2] = {(_Float16*)(ws + 436207616L), (_Float16*)(ws + 452984832L)};
    float* xz2[2]    = {(float*)(ws + 469762048L), (float*)(ws + 503316480L)};
    float* s1h       = (float*)(ws + 536870912L);
    float* s1c       = (float*)(ws + 537133056L);
    float* s2h       = (float*)(ws + 537395200L);
    float* s2c       = (float*)(ws + 537460736L);
    _Float16* U1p    = (_Float16*)(ws + 537526272L);
    _Float16* U2p    = (_Float16*)(ws + 537657344L);
    _Float16* W1T    = (_Float16*)(ws + 537665536L);
    _Float16* W2T    = (_Float16*)(ws + 537993216L);
    float* b1p       = (float*)(ws + 538025984L);
    float* b2p       = (float*)(ws + 538028032L);

    prep_weights<<<640, 256, 0, stream>>>(U1, U1p, U2, U2p, W1, W1T, W2, W2T,
                                          b1, b1p, b2, b2p);
    xsplit_chunk<<<10240, 256, 0, stream>>>(x, xh, 0);

#define MEGA(cA_, cB_, g1_, g2_, xs_) \
    mega<<<512, 512, 0, stream>>>(x, xh, W1T, b1p, W2T, b2p, U1p, U2p, \
        xz1[0], xz1[1], xz2[0], xz2[1], h1f[0], h1f[1], \
        s1h, s1c, s2h, s2c, cA_, cB_, g1_, g2_, xs_)

    MEGA(-1, -1, 0, -1, 1);   // prologue: gemm1(0) + xsplit(1)
    MEGA(0, -1, 1, -1, 2);    // lstm1(0) | gemm1(1) + xsplit(2)
    MEGA(1, -1, 2, 0, 3);     // lstm1(1) | gemm1(2), gemm2(0) + xsplit(3)
    MEGA(2, 0, 3, 1, -1);     // lstm1(2), lstm2(0) | gemm1(3), gemm2(1)
    MEGA(3, 1, -1, 2, -1);    // lstm1(3), lstm2(1) | gemm2(2)
    MEGA(-1, 2, -1, 3, -1);   // lstm2(2) | gemm2(3)
    MEGA(-1, 3, -1, -1, -1);  // lstm2(3)
#undef MEGA

    head_kernel<<<2, 256, 0, stream>>>(s2h, Wd, bd, out);
}

// Round 19
// 911.929 us; speedup vs baseline: 2.3907x; 2.3907x over previous
//
#include <hip/hip_runtime.h>
#include <math.h>

#define TC 128
#define NC 4
#define BATCH 512
#define T_TOTAL 512
#define D_IN 300
#define KP1 320
#define H1 128
#define G1 512
#define H2 32
#define NCLS 14

typedef unsigned short u16;
typedef __attribute__((ext_vector_type(8))) _Float16 f16x8;
typedef __attribute__((ext_vector_type(4))) float f32x4;

__device__ __forceinline__ float fexp2(float x) { return __builtin_amdgcn_exp2f(x); }
__device__ __forceinline__ float frcp(float x)  { return __builtin_amdgcn_rcpf(x); }
__device__ __forceinline__ float sig_f(float x) { return frcp(1.0f + fexp2(-1.44269504f * x)); }
__device__ __forceinline__ float th_f(float x)  { return 1.0f - 2.0f * frcp(1.0f + fexp2(2.88539008f * x)); }

// LDS-only barrier: no vmcnt(0) drain (global loads/stores stay in flight)
__device__ __forceinline__ void lds_barrier() {
    asm volatile("s_waitcnt lgkmcnt(0)" ::: "memory");
    __builtin_amdgcn_s_barrier();
}

// ---------------------------------------------------------------------------
// Prep: permuted-column f16 planes.
// ---------------------------------------------------------------------------
__global__ void prep_weights(const float* __restrict__ U1, _Float16* __restrict__ U1p,
                             const float* __restrict__ U2, _Float16* __restrict__ U2p,
                             const float* __restrict__ W1, _Float16* __restrict__ W1T,
                             const float* __restrict__ W2, _Float16* __restrict__ W2T,
                             const float* __restrict__ b1, float* __restrict__ b1p,
                             const float* __restrict__ b2, float* __restrict__ b2p)
{
    int idx = blockIdx.x * 256 + threadIdx.x;
    if (idx < 512 * 128) {
        int p = idx >> 7, k = idx & 127;
        int orig = ((p >> 4) & 3) * 128 + ((p >> 6) << 4) + (p & 15);
        U1p[p * 128 + k] = (_Float16)U1[k * 512 + orig];
    }
    if (idx < 512 * 320) {
        int p = idx / 320, k = idx % 320;
        int orig = ((p >> 4) & 3) * 128 + ((p >> 6) << 4) + (p & 15);
        W1T[p * 320 + k] = (_Float16)((k < D_IN) ? W1[k * 512 + orig] : 0.f);
    }
    if (idx < 128 * 128) {
        int p = idx >> 7, k = idx & 127;
        int orig = ((p >> 4) & 3) * 32 + ((p >> 6) << 4) + (p & 15);
        W2T[p * 128 + k] = (_Float16)W2[k * 128 + orig];
    }
    if (idx < 128 * 32) {
        int p = idx >> 5, k = idx & 31;
        int orig = ((p >> 4) & 3) * 32 + ((p >> 6) << 4) + (p & 15);
        U2p[p * 32 + k] = (_Float16)U2[k * 128 + orig];
    }
    if (idx < 512) {
        int orig = ((idx >> 4) & 3) * 128 + ((idx >> 6) << 4) + (idx & 15);
        b1p[idx] = b1[orig];
    }
    if (idx < 128) {
        int orig = ((idx >> 4) & 3) * 32 + ((idx >> 6) << 4) + (idx & 15);
        b2p[idx] = b2[orig];
    }
}

// ---------------------------------------------------------------------------
// xsplit: x chunk -> f16 plane
// ---------------------------------------------------------------------------
__device__ __forceinline__ void xsplit_item(const float* __restrict__ x,
                                            _Float16* __restrict__ xh,
                                            int chunk, long i)
{
    int rr = (int)(i / 40), s = (int)(i % 40);
    int b = rr >> 7, tt = rr & 127;
    long m = (long)b * T_TOTAL + (long)chunk * TC + tt;
    int k0 = s * 8;
    const float* xr = x + m * D_IN + k0;
    float4 v0 = {0.f, 0.f, 0.f, 0.f}, v1 = {0.f, 0.f, 0.f, 0.f};
    if (s < 37) {
        v0 = *(const float4*)(xr);
        v1 = *(const float4*)(xr + 4);
    } else if (s == 37) {
        v0 = *(const float4*)(xr);
    }
    f16x8 o;
    o[0] = (_Float16)v0.x; o[1] = (_Float16)v0.y;
    o[2] = (_Float16)v0.z; o[3] = (_Float16)v0.w;
    o[4] = (_Float16)v1.x; o[5] = (_Float16)v1.y;
    o[6] = (_Float16)v1.z; o[7] = (_Float16)v1.w;
    *(f16x8*)(xh + m * KP1 + k0) = o;
}

__global__ void xsplit_chunk(const float* __restrict__ x, _Float16* __restrict__ xh, int chunk)
{
    long gid = (long)blockIdx.x * 256 + threadIdx.x;
    if (gid >= 65536L * 40) return;
    xsplit_item(x, xh, chunk, gid);
}

__device__ __forceinline__ void xsplit_role(const float* __restrict__ x,
                                            _Float16* __restrict__ xh,
                                            int chunk, int cwid, int ncw)
{
    const int tid = threadIdx.x;
    for (long i = (long)cwid * 512 + tid; i < 65536L * 40; i += (long)ncw * 512)
        xsplit_item(x, xh, chunk, i);
}

// ---------------------------------------------------------------------------
// GEMM m-block: WG computes C[128 rows][ALL N = NT*128 cols], row-major C.
// ---------------------------------------------------------------------------
template<int NK, int NT, bool XMAP>
__device__ __forceinline__ void gemm_mblock(
    const _Float16* __restrict__ A, const _Float16* __restrict__ B,
    const float* __restrict__ bias, float* __restrict__ C,
    int m0, int chunk)
{
    const int Nc = NT * 128;
    const int tid = threadIdx.x;
    const int l = tid & 63, w = tid >> 6;
    const int wm = w >> 2, wn = w & 3;
    const int lr = l & 15, q = l >> 4;
    const int koff = q * 8;
    const int LDA = NK * 32;

    const _Float16* ap[4];
#pragma unroll
    for (int fi = 0; fi < 4; fi++) {
        int m = m0 + wm * 64 + fi * 16 + lr;
        long row = XMAP ? ((long)(m >> 7) * T_TOTAL + (long)chunk * TC + (m & (TC - 1)))
                        : (long)m;
        ap[fi] = A + row * LDA + koff;
    }
    const _Float16* bp[NT * 2];
    float bv[NT * 2];
#pragma unroll
    for (int fj = 0; fj < NT * 2; fj++) {
        int col = (fj >> 1) * 128 + wn * 32 + (fj & 1) * 16 + lr;
        bp[fj] = B + (long)col * LDA + koff;
        bv[fj] = bias[col];
    }

    f32x4 acc[4][NT * 2];
#pragma unroll
    for (int fi = 0; fi < 4; fi++)
#pragma unroll
        for (int fj = 0; fj < NT * 2; fj++)
            acc[fi][fj] = (f32x4){bv[fj], bv[fj], bv[fj], bv[fj]};

    f16x8 acur[4], anxt[4];
#pragma unroll
    for (int fi = 0; fi < 4; fi++)
        acur[fi] = *(const f16x8*)(ap[fi]);

#pragma unroll
    for (int ks = 0; ks < NK; ks++) {
        f16x8 bb[NT * 2];
#pragma unroll
        for (int fj = 0; fj < NT * 2; fj++)
            bb[fj] = *(const f16x8*)(bp[fj] + ks * 32);
        if (ks + 1 < NK) {
#pragma unroll
            for (int fi = 0; fi < 4; fi++)
                anxt[fi] = *(const f16x8*)(ap[fi] + (ks + 1) * 32);
        }
#pragma unroll
        for (int fi = 0; fi < 4; fi++)
#pragma unroll
            for (int fj = 0; fj < NT * 2; fj++)
                acc[fi][fj] = __builtin_amdgcn_mfma_f32_16x16x32_f16(acur[fi], bb[fj], acc[fi][fj], 0, 0, 0);
#pragma unroll
        for (int fi = 0; fi < 4; fi++)
            acur[fi] = anxt[fi];
    }

#pragma unroll
    for (int fi = 0; fi < 4; fi++) {
        int mrow = m0 + wm * 64 + fi * 16 + q * 4;
#pragma unroll
        for (int fj = 0; fj < NT * 2; fj++) {
            int col = (fj >> 1) * 128 + wn * 32 + (fj & 1) * 16 + lr;
#pragma unroll
            for (int rr = 0; rr < 4; rr++)
                C[(long)(mrow + rr) * Nc + col] = acc[fi][fj][rr];
        }
    }
}

// ---------------------------------------------------------------------------
// Role A: lstm1 scan, 8 rows/WG over 64 WGs, distance-1 prefetch.
// ROW REMAP (no shuffles): batch row r at A/D-row p(r) = (r>>1)*4 + (r&1)
// in {0,1,4,5,8,9,12,13}; D-layout row=(lane>>4)*4+reg puts batch rows
// 2q,2q+1 in EVERY lane's acc regs 0,1 -> each lane activates 2 rows from
// its own registers. Zero A-rows 4q+2,4q+3 (outputs discarded).
// ---------------------------------------------------------------------------
#define L1_DECL(P) float P##0, P##1, P##2, P##3, P##4, P##5, P##6, P##7;

#define L1_LOAD(P, T)                                                             \
    P##0 = xz[xrA + (long)(T) * 512 +  0]; P##1 = xz[xrB + (long)(T) * 512 +  0]; \
    P##2 = xz[xrA + (long)(T) * 512 + 16]; P##3 = xz[xrB + (long)(T) * 512 + 16]; \
    P##4 = xz[xrA + (long)(T) * 512 + 32]; P##5 = xz[xrB + (long)(T) * 512 + 32]; \
    P##6 = xz[xrA + (long)(T) * 512 + 48]; P##7 = xz[xrB + (long)(T) * 512 + 48];

#define L1_STEP(T, PB, XC, XN)                                                    \
{                                                                                 \
    f16x8 ah0 = *(const f16x8*)&Ah[(PB) * 2048 + lr * 128 + (((q     ) ^ lr) << 3)]; \
    f16x8 ah1 = *(const f16x8*)&Ah[(PB) * 2048 + lr * 128 + (((q +  4) ^ lr) << 3)]; \
    f16x8 ah2 = *(const f16x8*)&Ah[(PB) * 2048 + lr * 128 + (((q +  8) ^ lr) << 3)]; \
    f16x8 ah3 = *(const f16x8*)&Ah[(PB) * 2048 + lr * 128 + (((q + 12) ^ lr) << 3)]; \
    if ((T) + 1 < TC) { L1_LOAD(XN, (T) + 1) }                                    \
    f32x4 a0 = (f32x4){XC##0, XC##1, 0.f, 0.f};                                   \
    f32x4 a1 = (f32x4){XC##2, XC##3, 0.f, 0.f};                                   \
    f32x4 a2 = (f32x4){XC##4, XC##5, 0.f, 0.f};                                   \
    f32x4 a3 = (f32x4){XC##6, XC##7, 0.f, 0.f};                                   \
    a0 = __builtin_amdgcn_mfma_f32_16x16x32_f16(ah0, uh00, a0, 0, 0, 0);          \
    a1 = __builtin_amdgcn_mfma_f32_16x16x32_f16(ah0, uh10, a1, 0, 0, 0);          \
    a2 = __builtin_amdgcn_mfma_f32_16x16x32_f16(ah0, uh20, a2, 0, 0, 0);          \
    a3 = __builtin_amdgcn_mfma_f32_16x16x32_f16(ah0, uh30, a3, 0, 0, 0);          \
    a0 = __builtin_amdgcn_mfma_f32_16x16x32_f16(ah1, uh01, a0, 0, 0, 0);          \
    a1 = __builtin_amdgcn_mfma_f32_16x16x32_f16(ah1, uh11, a1, 0, 0, 0);          \
    a2 = __builtin_amdgcn_mfma_f32_16x16x32_f16(ah1, uh21, a2, 0, 0, 0);          \
    a3 = __builtin_amdgcn_mfma_f32_16x16x32_f16(ah1, uh31, a3, 0, 0, 0);          \
    a0 = __builtin_amdgcn_mfma_f32_16x16x32_f16(ah2, uh02, a0, 0, 0, 0);          \
    a1 = __builtin_amdgcn_mfma_f32_16x16x32_f16(ah2, uh12, a1, 0, 0, 0);          \
    a2 = __builtin_amdgcn_mfma_f32_16x16x32_f16(ah2, uh22, a2, 0, 0, 0);          \
    a3 = __builtin_amdgcn_mfma_f32_16x16x32_f16(ah2, uh32, a3, 0, 0, 0);          \
    a0 = __builtin_amdgcn_mfma_f32_16x16x32_f16(ah3, uh03, a0, 0, 0, 0);          \
    a1 = __builtin_amdgcn_mfma_f32_16x16x32_f16(ah3, uh13, a1, 0, 0, 0);          \
    a2 = __builtin_amdgcn_mfma_f32_16x16x32_f16(ah3, uh23, a2, 0, 0, 0);          \
    a3 = __builtin_amdgcn_mfma_f32_16x16x32_f16(ah3, uh33, a3, 0, 0, 0);          \
    {                                                                             \
        float iv = sig_f(a0[0]), fv = sig_f(a1[0]), gv = th_f(a2[0]), ov = sig_f(a3[0]); \
        cstA = fv * cstA + iv * gv;                                               \
        float hv = ov * th_f(cstA);                                               \
        _Float16 hh = (_Float16)hv;                                               \
        Ah[((PB) ^ 1) * 2048 + pA * 128 + idxA] = hh;                             \
        h1f[((long)(b0 + rA) * TC + (T)) * 128 + cn] = hh;                        \
        if ((T) == TC - 1) {                                                      \
            s1h[(long)(b0 + rA) * 128 + cn] = hv;                                 \
            s1c[(long)(b0 + rA) * 128 + cn] = cstA;                               \
        }                                                                         \
    }                                                                             \
    {                                                                             \
        float iv = sig_f(a0[1]), fv = sig_f(a1[1]), gv = th_f(a2[1]), ov = sig_f(a3[1]); \
        cstB = fv * cstB + iv * gv;                                               \
        float hv = ov * th_f(cstB);                                               \
        _Float16 hh = (_Float16)hv;                                               \
        Ah[((PB) ^ 1) * 2048 + pB * 128 + idxB] = hh;                             \
        h1f[((long)(b0 + rB) * TC + (T)) * 128 + cn] = hh;                        \
        if ((T) == TC - 1) {                                                      \
            s1h[(long)(b0 + rB) * 128 + cn] = hv;                                 \
            s1c[(long)(b0 + rB) * 128 + cn] = cstB;                               \
        }                                                                         \
    }                                                                             \
    lds_barrier();                                                                \
}

static __device__ __forceinline__ void lstm1_role(
    const float* __restrict__ xz, const _Float16* __restrict__ U1p,
    _Float16* __restrict__ h1f, float* __restrict__ s1h, float* __restrict__ s1c,
    int first, char* smc)
{
    const int tid = threadIdx.x;
    const int l = tid & 63, w = tid >> 6;
    const int lr = l & 15, q = l >> 4;
    const int koff = q * 8;
    const int cn = w * 16 + lr;
    const int b0 = blockIdx.x * 8;
    const int p0 = w * 64 + lr;
    const int rA = 2 * q, rB = 2 * q + 1;        // batch rows (within 8)
    const int pA = 4 * q, pB = 4 * q + 1;        // A/D-tile row positions
    const int idxA = (((cn >> 3) ^ pA) << 3) + (cn & 7);
    const int idxB = (((cn >> 3) ^ pB) << 3) + (cn & 7);

    _Float16* Ah = (_Float16*)smc;   // [2][16][128] f16

    const long xrA = ((long)(b0 + rA) * TC) * 512 + p0;
    const long xrB = ((long)(b0 + rB) * TC) * 512 + p0;

    const _Float16* ub = U1p + (long)(w * 64 + lr) * 128 + koff;
    f16x8 uh00 = *(const f16x8*)(ub +    0 * 128 +  0);
    f16x8 uh01 = *(const f16x8*)(ub +    0 * 128 + 32);
    f16x8 uh02 = *(const f16x8*)(ub +    0 * 128 + 64);
    f16x8 uh03 = *(const f16x8*)(ub +    0 * 128 + 96);
    f16x8 uh10 = *(const f16x8*)(ub +   16 * 128 +  0);
    f16x8 uh11 = *(const f16x8*)(ub +   16 * 128 + 32);
    f16x8 uh12 = *(const f16x8*)(ub +   16 * 128 + 64);
    f16x8 uh13 = *(const f16x8*)(ub +   16 * 128 + 96);
    f16x8 uh20 = *(const f16x8*)(ub +   32 * 128 +  0);
    f16x8 uh21 = *(const f16x8*)(ub +   32 * 128 + 32);
    f16x8 uh22 = *(const f16x8*)(ub +   32 * 128 + 64);
    f16x8 uh23 = *(const f16x8*)(ub +   32 * 128 + 96);
    f16x8 uh30 = *(const f16x8*)(ub +   48 * 128 +  0);
    f16x8 uh31 = *(const f16x8*)(ub +   48 * 128 + 32);
    f16x8 uh32 = *(const f16x8*)(ub +   48 * 128 + 64);
    f16x8 uh33 = *(const f16x8*)(ub +   48 * 128 + 96);

    // init: valid rows pA,pB from state; rows 4q+2,4q+3 zeroed in BOTH buffers
    float hA = 0.f, hB = 0.f, cstA = 0.f, cstB = 0.f;
    if (!first) {
        hA = s1h[(long)(b0 + rA) * 128 + cn];
        cstA = s1c[(long)(b0 + rA) * 128 + cn];
        hB = s1h[(long)(b0 + rB) * 128 + cn];
        cstB = s1c[(long)(b0 + rB) * 128 + cn];
    }
    Ah[pA * 128 + idxA] = (_Float16)hA;
    Ah[pB * 128 + idxB] = (_Float16)hB;
    {
        int p2 = 4 * q + 2, p3 = 4 * q + 3;
        int idx2 = (((cn >> 3) ^ p2) << 3) + (cn & 7);
        int idx3 = (((cn >> 3) ^ p3) << 3) + (cn & 7);
        Ah[p2 * 128 + idx2] = (_Float16)0.f;
        Ah[p3 * 128 + idx3] = (_Float16)0.f;
        Ah[2048 + p2 * 128 + idx2] = (_Float16)0.f;
        Ah[2048 + p3 * 128 + idx3] = (_Float16)0.f;
    }
    lds_barrier();

    L1_DECL(xa) L1_DECL(xb)
    L1_LOAD(xa, 0)

    for (int t = 0; t < TC; t += 2) {
        L1_STEP(t,     0, xa, xb)
        L1_STEP(t + 1, 1, xb, xa)
    }
}

// ---------------------------------------------------------------------------
// Role B: lstm2 scan, 16 rows/WG, WGs [64,96), waves 0-1 active.
// ---------------------------------------------------------------------------
#define L2_DECL(P) float P##00, P##01, P##02, P##03, P##10, P##11, P##12, P##13, \
                         P##20, P##21, P##22, P##23, P##30, P##31, P##32, P##33;

#define L2_LOAD(P, T)                                                             \
    P##00 = xz2[yr0 + (long)(T) * 128 +  0]; P##01 = xz2[yr1 + (long)(T) * 128 +  0]; \
    P##02 = xz2[yr2 + (long)(T) * 128 +  0]; P##03 = xz2[yr3 + (long)(T) * 128 +  0]; \
    P##10 = xz2[yr0 + (long)(T) * 128 + 16]; P##11 = xz2[yr1 + (long)(T) * 128 + 16]; \
    P##12 = xz2[yr2 + (long)(T) * 128 + 16]; P##13 = xz2[yr3 + (long)(T) * 128 + 16]; \
    P##20 = xz2[yr0 + (long)(T) * 128 + 32]; P##21 = xz2[yr1 + (long)(T) * 128 + 32]; \
    P##22 = xz2[yr2 + (long)(T) * 128 + 32]; P##23 = xz2[yr3 + (long)(T) * 128 + 32]; \
    P##30 = xz2[yr0 + (long)(T) * 128 + 48]; P##31 = xz2[yr1 + (long)(T) * 128 + 48]; \
    P##32 = xz2[yr2 + (long)(T) * 128 + 48]; P##33 = xz2[yr3 + (long)(T) * 128 + 48];

#define L2_STEP(T, PB, XC, XN)                                                    \
{                                                                                 \
    if (act) {                                                                    \
        f16x8 ah = *(const f16x8*)&Ah[(PB) * 640 + lr * 40 + koff];               \
        if ((T) + 1 < TC) { L2_LOAD(XN, (T) + 1) }                                \
        f32x4 a0 = (f32x4){XC##00, XC##01, XC##02, XC##03};                       \
        f32x4 a1 = (f32x4){XC##10, XC##11, XC##12, XC##13};                       \
        f32x4 a2 = (f32x4){XC##20, XC##21, XC##22, XC##23};                       \
        f32x4 a3 = (f32x4){XC##30, XC##31, XC##32, XC##33};                       \
        a0 = __builtin_amdgcn_mfma_f32_16x16x32_f16(ah, uh0, a0, 0, 0, 0);        \
        a1 = __builtin_amdgcn_mfma_f32_16x16x32_f16(ah, uh1, a1, 0, 0, 0);        \
        a2 = __builtin_amdgcn_mfma_f32_16x16x32_f16(ah, uh2, a2, 0, 0, 0);        \
        a3 = __builtin_amdgcn_mfma_f32_16x16x32_f16(ah, uh3, a3, 0, 0, 0);        \
        _Pragma("unroll")                                                         \
        for (int r = 0; r < 4; r++) {                                             \
            float iv = sig_f(a0[r]);                                              \
            float fv = sig_f(a1[r]);                                              \
            float gv = th_f(a2[r]);                                               \
            float ov = sig_f(a3[r]);                                              \
            float cc = (r == 0) ? cst0 : (r == 1) ? cst1 : (r == 2) ? cst2 : cst3;\
            cc = fv * cc + iv * gv;                                               \
            float hv = ov * th_f(cc);                                             \
            if (r == 0) cst0 = cc; else if (r == 1) cst1 = cc;                    \
            else if (r == 2) cst2 = cc; else cst3 = cc;                           \
            int rw = (q << 2) + r;                                                \
            Ah[((PB) ^ 1) * 640 + rw * 40 + cn] = (_Float16)hv;                   \
            if ((T) == TC - 1) {                                                  \
                s2h[(long)(b0 + rw) * 32 + cn] = hv;                              \
                s2c[(long)(b0 + rw) * 32 + cn] = cc;                              \
            }                                                                     \
        }                                                                         \
    }                                                                             \
    lds_barrier();                                                                \
}

static __device__ __forceinline__ void lstm2_role(
    const float* __restrict__ xz2, const _Float16* __restrict__ U2p,
    float* __restrict__ s2h, float* __restrict__ s2c, int first, char* smc)
{
    const int tid = threadIdx.x;
    const int b0 = (blockIdx.x - 64) * 16;
    const bool act = tid < 128;
    const int l = tid & 63, w = (tid >> 6) & 1;
    const int lr = l & 15, q = l >> 4;
    const int koff = q * 8;
    const int cn = w * 16 + lr;
    const int p0 = w * 64 + lr;
    const int bq = b0 + q * 4;

    const long yr0 = ((long)(bq + 0) * TC) * 128 + p0;
    const long yr1 = ((long)(bq + 1) * TC) * 128 + p0;
    const long yr2 = ((long)(bq + 2) * TC) * 128 + p0;
    const long yr3 = ((long)(bq + 3) * TC) * 128 + p0;

    _Float16* Ah = (_Float16*)smc;   // [2][16][40]

    f16x8 uh0 = {}, uh1 = {}, uh2 = {}, uh3 = {};
    float cst0 = 0.f, cst1 = 0.f, cst2 = 0.f, cst3 = 0.f;
    L2_DECL(xa) L2_DECL(xb)

    if (act) {
        const _Float16* ub = U2p + (long)(w * 64 + lr) * 32 + koff;
        uh0 = *(const f16x8*)(ub +  0 * 32);
        uh1 = *(const f16x8*)(ub + 16 * 32);
        uh2 = *(const f16x8*)(ub + 32 * 32);
        uh3 = *(const f16x8*)(ub + 48 * 32);
#pragma unroll
        for (int r = 0; r < 4; r++) {
            int rw = q * 4 + r;
            float h = 0.f, c = 0.f;
            if (!first) {
                h = s2h[(long)(b0 + rw) * 32 + cn];
                c = s2c[(long)(b0 + rw) * 32 + cn];
            }
            if (r == 0) cst0 = c; else if (r == 1) cst1 = c;
            else if (r == 2) cst2 = c; else cst3 = c;
            Ah[rw * 40 + cn] = (_Float16)h;
        }
        L2_LOAD(xa, 0)
    }
    lds_barrier();

    for (int t = 0; t < TC; t += 2) {
        L2_STEP(t,     0, xa, xb)
        L2_STEP(t + 1, 1, xb, xa)
    }
}

// ---------------------------------------------------------------------------
// Fused mega kernel: A = lstm1(cA) [WG 0-63], B = lstm2(cB) [WG 64-95],
// C = xsplit(xs) + gemm1(g1) + gemm2(g2) [remaining WGs].
// ---------------------------------------------------------------------------
__global__ void
__attribute__((amdgpu_flat_work_group_size(512, 512)))
__attribute__((amdgpu_waves_per_eu(2, 2)))
mega(
    const float* __restrict__ x, _Float16* __restrict__ xh,
    const _Float16* __restrict__ W1T, const float* __restrict__ b1p,
    const _Float16* __restrict__ W2T, const float* __restrict__ b2p,
    const _Float16* __restrict__ U1p, const _Float16* __restrict__ U2p,
    float* xz1_0, float* xz1_1, float* xz2_0, float* xz2_1,
    _Float16* h1f_0, _Float16* h1f_1,
    float* s1h, float* s1c, float* s2h, float* s2c,
    int cA, int cB, int g1, int g2, int xs)
{
    __shared__ __align__(16) char sm[8192];
    int bid = blockIdx.x;

    if (cA >= 0 && bid < 64) {
        const float* xz = (cA & 1) ? xz1_1 : xz1_0;
        _Float16* hf = (cA & 1) ? h1f_1 : h1f_0;
        lstm1_role(xz, U1p, hf, s1h, s1c, cA == 0, sm);
        return;
    }
    if (cB >= 0 && bid >= 64 && bid < 96) {
        const float* xz2 = (cB & 1) ? xz2_1 : xz2_0;
        lstm2_role(xz2, U2p, s2h, s2c, cB == 0, sm);
        return;
    }
    int cwid = bid, ncw = 256;
    if (cA >= 0) { ncw -= 64; cwid -= 64; }
    if (cB >= 0) { ncw -= 32; if (bid >= 96) cwid -= 32; }
    if (xs >= 0) xsplit_role(x, xh, xs, cwid, ncw);
    int ng1 = (g1 >= 0) ? (BATCH * TC / 128) : 0;   // 512 m-blocks
    int ng2 = (g2 >= 0) ? (BATCH * TC / 128) : 0;   // 512 m-blocks
    float* xz1o = (g1 >= 0 && (g1 & 1)) ? xz1_1 : xz1_0;
    float* xz2o = (g2 >= 0 && (g2 & 1)) ? xz2_1 : xz2_0;
    const _Float16* hf = (g2 >= 0 && (g2 & 1)) ? h1f_1 : h1f_0;
    for (int it = cwid; it < ng1 + ng2; it += ncw) {
        if (it < ng1)
            gemm_mblock<10, 4, true>(xh, W1T, b1p, xz1o, it * 128, g1);
        else
            gemm_mblock<4, 1, false>(hf, W2T, b2p, xz2o, (it - ng1) * 128, 0);
    }
}

// ---------------------------------------------------------------------------
// Head: out = softmax(h2_last @ Wd + bd)   [512,32]@[32,14]
// ---------------------------------------------------------------------------
__global__ __launch_bounds__(256)
void head_kernel(const float* __restrict__ h2, const float* __restrict__ Wd,
                 const float* __restrict__ bd, float* __restrict__ out)
{
    int b = blockIdx.x * 256 + threadIdx.x;
    float h[H2];
#pragma unroll
    for (int k = 0; k < H2; k += 4)
        *(float4*)&h[k] = *(const float4*)&h2[b * H2 + k];

    float lg[NCLS];
#pragma unroll
    for (int c = 0; c < NCLS; c++) lg[c] = bd[c];
#pragma unroll
    for (int k = 0; k < H2; k++) {
        float hv = h[k];
#pragma unroll
        for (int c = 0; c < NCLS; c++)
            lg[c] += hv * Wd[k * NCLS + c];
    }
    float m = lg[0];
#pragma unroll
    for (int c = 1; c < NCLS; c++) m = fmaxf(m, lg[c]);
    float s = 0.f;
#pragma unroll
    for (int c = 0; c < NCLS; c++) { lg[c] = __expf(lg[c] - m); s += lg[c]; }
    float inv = __fdividef(1.0f, s);
#pragma unroll
    for (int c = 0; c < NCLS; c++) out[b * NCLS + c] = lg[c] * inv;
}

// ---------------------------------------------------------------------------
extern "C" void kernel_launch(void* const* d_in, const int* in_sizes, int n_in,
                              void* d_out, int out_size, void* d_ws, size_t ws_size,
                              hipStream_t stream)
{
    const float* x  = (const float*)d_in[0];
    const float* W1 = (const float*)d_in[1];
    const float* U1 = (const float*)d_in[2];
    const float* b1 = (const float*)d_in[3];
    const float* W2 = (const float*)d_in[4];
    const float* U2 = (const float*)d_in[5];
    const float* b2 = (const float*)d_in[6];
    const float* Wd = (const float*)d_in[7];
    const float* bd = (const float*)d_in[8];
    float* out = (float*)d_out;

    char* ws = (char*)d_ws;
    float* xz1[2]    = {(float*)(ws + 0L),         (float*)(ws + 134217728L)};
    _Float16* xh     = (_Float16*)(ws + 268435456L);               // 167772160
    _Float16* h1f[2] = {(_Float16*)(ws + 436207616L), (_Float16*)(ws + 452984832L)};
    float* xz2[2]    = {(float*)(ws + 469762048L), (float*)(ws + 503316480L)};
    float* s1h       = (float*)(ws + 536870912L);
    float* s1c       = (float*)(ws + 537133056L);
    float* s2h       = (float*)(ws + 537395200L);
    float* s2c       = (float*)(ws + 537460736L);
    _Float16* U1p    = (_Float16*)(ws + 537526272L);
    _Float16* U2p    = (_Float16*)(ws + 537657344L);
    _Float16* W1T    = (_Float16*)(ws + 537665536L);
    _Float16* W2T    = (_Float16*)(ws + 537993216L);
    float* b1p       = (float*)(ws + 538025984L);
    float* b2p       = (float*)(ws + 538028032L);

    prep_weights<<<640, 256, 0, stream>>>(U1, U1p, U2, U2p, W1, W1T, W2, W2T,
                                          b1, b1p, b2, b2p);
    xsplit_chunk<<<10240, 256, 0, stream>>>(x, xh, 0);

#define MEGA(cA_, cB_, g1_, g2_, xs_) \
    mega<<<256, 512, 0, stream>>>(x, xh, W1T, b1p, W2T, b2p, U1p, U2p, \
        xz1[0], xz1[1], xz2[0], xz2[1], h1f[0], h1f[1], \
        s1h, s1c, s2h, s2c, cA_, cB_, g1_, g2_, xs_)

    MEGA(-1, -1, 0, -1, 1);   // prologue: gemm1(0) + xsplit(1)
    MEGA(0, -1, 1, -1, 2);    // lstm1(0) | gemm1(1) + xsplit(2)
    MEGA(1, -1, 2, 0, 3);     // lstm1(1) | gemm1(2), gemm2(0) + xsplit(3)
    MEGA(2, 0, 3, 1, -1);     // lstm1(2), lstm2(0) | gemm1(3), gemm2(1)
    MEGA(3, 1, -1, 2, -1);    // lstm1(3), lstm2(1) | gemm2(2)
    MEGA(-1, 2, -1, 3, -1);   // lstm2(2) | gemm2(3)
    MEGA(-1, 3, -1, -1, -1);  // lstm2(3)
#undef MEGA

    head_kernel<<<2, 256, 0, stream>>>(s2h, Wd, bd, out);
}